// Round 1
// baseline (836.436 us; speedup 1.0000x reference)
//
#include <hip/hip_runtime.h>

// ArDCA loss: loss = -sum_{m,i} W[m] * log_softmax(h[i,:] + sum_{j<i} J[i,j,:,X[m,j]])[X[m,i]]
//             + 1e-6 * sum h^2 + 1e-4 * sum_{j<i} J^2
// M=8192, L=256, Q=21. Output: single fp32 scalar.

#define M_SEQ 8192
#define L_POS 256
#define Q_SYM 21
#define QQ    441           // Q*Q
#define JC    16            // j-chunk staged to LDS per iteration
#define ROWP  24            // padded floats per b-row in LDS (96 B, float4-aligned)
#define JL_STRIDE (Q_SYM * ROWP)   // 504 floats per jc

__device__ __forceinline__ float wave_block_reduce(float v, float* red, int tid) {
    #pragma unroll
    for (int off = 32; off > 0; off >>= 1) v += __shfl_down(v, off, 64);
    if ((tid & 63) == 0) red[tid >> 6] = v;
    __syncthreads();
    return red[0] + red[1] + red[2] + red[3];
}

__global__ void zero_out(float* __restrict__ out) { out[0] = 0.0f; }

// L2 regularization terms: 1e-4 * sum_{j<i} J[i,j,:,:]^2 + 1e-6 * sum h^2
__global__ __launch_bounds__(256) void reg_kernel(const float* __restrict__ J,
                                                  const float* __restrict__ h,
                                                  float* __restrict__ out) {
    __shared__ float red[4];
    const int tid = threadIdx.x;
    const long long NJ4 = (long long)L_POS * L_POS * QQ / 4;   // 7,225,344 float4s
    const long long stride = (long long)gridDim.x * blockDim.x;
    float lsum = 0.0f;
    const float4* J4 = (const float4*)J;
    for (long long t = (long long)blockIdx.x * blockDim.x + tid; t < NJ4; t += stride) {
        float4 f = J4[t];
        int base = (int)(t * 4);
        int p0 = (base + 0) / QQ;
        int p1 = (base + 1) / QQ;
        int p2 = (base + 2) / QQ;
        int p3 = (base + 3) / QQ;
        // pair index p = i*256 + j  ->  i = p>>8, j = p&255 ; keep j < i
        float s = 0.0f;
        s += ((p0 & 255) < (p0 >> 8)) ? f.x * f.x : 0.0f;
        s += ((p1 & 255) < (p1 >> 8)) ? f.y * f.y : 0.0f;
        s += ((p2 & 255) < (p2 >> 8)) ? f.z * f.z : 0.0f;
        s += ((p3 & 255) < (p3 >> 8)) ? f.w * f.w : 0.0f;
        lsum += s;
    }
    lsum *= 1e-4f;
    int gid = blockIdx.x * blockDim.x + tid;
    if (gid < L_POS * Q_SYM) {
        float hv = h[gid];
        lsum += 1e-6f * hv * hv;
    }
    float tot = wave_block_reduce(lsum, red, tid);
    if (tid == 0) atomicAdd(out, tot);
}

// One block per (m-chunk of 256, i). Each thread owns one m.
// Stages J[i, j0..j0+15, a, b] into LDS transposed to JL[jc][b][a] so the
// per-thread gather of 21 floats (fixed b = X[m,j]) is contiguous -> ds_read_b128.
__global__ __launch_bounds__(256) void pair_nll_kernel(const int* __restrict__ X,
                                                       const float* __restrict__ W,
                                                       const float* __restrict__ h,
                                                       const float* __restrict__ J,
                                                       float* __restrict__ out) {
    __shared__ float JL[JC * JL_STRIDE];   // 16*504*4 = 32256 B
    __shared__ float red[4];

    const int tid = threadIdx.x;
    const int i  = blockIdx.y;
    const int m  = blockIdx.x * 256 + tid;
    const int* xrow = X + (size_t)m * L_POS;

    float acc[Q_SYM];
    #pragma unroll
    for (int a = 0; a < Q_SYM; ++a) acc[a] = 0.0f;

    for (int j0 = 0; j0 < i; j0 += JC) {
        const float* Jsrc = J + ((size_t)i * L_POS + j0) * QQ;
        __syncthreads();   // protect previous chunk's LDS reads
        // stage + transpose: JL[jc*504 + b*24 + a] = J[i, j0+jc, a, b]
        for (int idx = tid; idx < JC * QQ; idx += 256) {
            int jc  = idx / QQ;
            int rem = idx - jc * QQ;
            int a   = rem / Q_SYM;
            int b   = rem - a * Q_SYM;
            JL[jc * JL_STRIDE + b * ROWP + a] = Jsrc[idx];
        }
        __syncthreads();

        // this thread's 16 X values (row-contiguous, vectorized)
        int4 xa = *(const int4*)(xrow + j0);
        int4 xb = *(const int4*)(xrow + j0 + 4);
        int4 xc = *(const int4*)(xrow + j0 + 8);
        int4 xd = *(const int4*)(xrow + j0 + 12);
        int xv[JC] = {xa.x, xa.y, xa.z, xa.w, xb.x, xb.y, xb.z, xb.w,
                      xc.x, xc.y, xc.z, xc.w, xd.x, xd.y, xd.z, xd.w};

        #pragma unroll
        for (int jc = 0; jc < JC; ++jc) {
            if (j0 + jc < i) {   // block-uniform guard (scalar branch)
                int b = xv[jc];
                const float* row = JL + jc * JL_STRIDE + b * ROWP;
                float4 f0 = *(const float4*)(row + 0);
                float4 f1 = *(const float4*)(row + 4);
                float4 f2 = *(const float4*)(row + 8);
                float4 f3 = *(const float4*)(row + 12);
                float4 f4 = *(const float4*)(row + 16);
                float  g0 = row[20];
                acc[0]  += f0.x; acc[1]  += f0.y; acc[2]  += f0.z; acc[3]  += f0.w;
                acc[4]  += f1.x; acc[5]  += f1.y; acc[6]  += f1.z; acc[7]  += f1.w;
                acc[8]  += f2.x; acc[9]  += f2.y; acc[10] += f2.z; acc[11] += f2.w;
                acc[12] += f3.x; acc[13] += f3.y; acc[14] += f3.z; acc[15] += f3.w;
                acc[16] += f4.x; acc[17] += f4.y; acc[18] += f4.z; acc[19] += f4.w;
                acc[20] += g0;
            }
        }
    }

    // logits = h[i,:] + pair ; log-softmax ; pick gold = X[m,i]
    const float* hrow = h + i * Q_SYM;
    float logits[Q_SYM];
    float mx = -3.4e38f;
    #pragma unroll
    for (int a = 0; a < Q_SYM; ++a) {
        float l = hrow[a] + acc[a];
        logits[a] = l;
        mx = fmaxf(mx, l);
    }
    float s = 0.0f;
    #pragma unroll
    for (int a = 0; a < Q_SYM; ++a) s += __expf(logits[a] - mx);
    int g = xrow[i];
    float gold = 0.0f;
    #pragma unroll
    for (int a = 0; a < Q_SYM; ++a) gold = (a == g) ? logits[a] : gold;
    float logp = gold - mx - __logf(s);
    float v = -W[m] * logp;

    __syncthreads();   // JL/red reuse safety before reduction
    float tot = wave_block_reduce(v, red, tid);
    if (tid == 0) atomicAdd(out, tot);
}

extern "C" void kernel_launch(void* const* d_in, const int* in_sizes, int n_in,
                              void* d_out, int out_size, void* d_ws, size_t ws_size,
                              hipStream_t stream) {
    const int*   X = (const int*)d_in[0];
    const float* W = (const float*)d_in[1];
    const float* h = (const float*)d_in[2];
    const float* J = (const float*)d_in[3];
    float* out = (float*)d_out;

    hipLaunchKernelGGL(zero_out, dim3(1), dim3(1), 0, stream, out);
    hipLaunchKernelGGL(reg_kernel, dim3(1024), dim3(256), 0, stream, J, h, out);
    dim3 grid(M_SEQ / 256, L_POS);
    hipLaunchKernelGGL(pair_nll_kernel, grid, dim3(256), 0, stream, X, W, h, J, out);
}

// Round 2
// 810.278 us; speedup vs baseline: 1.0323x; 1.0323x over previous
//
#include <hip/hip_runtime.h>

// ArDCA loss: loss = -sum_{m,i} W[m] * log_softmax(h[i,:] + sum_{j<i} J[i,j,:,X[m,j]])[X[m,i]]
//             + 1e-6 * sum h^2 + 1e-4 * sum_{j<i} J^2
// M=8192, L=256, Q=21. Output: single fp32 scalar.
//
// R2: XOR-swizzled LDS layout. Row (jc,b) = 32 floats (128 B, spans all 32 banks).
// Element a lives at float4-slot (a>>2)^(b&7). Reader xors the same way, so the
// <=21 distinct b addresses per wave spread over all 8 bank-groups with <=3-way
// collisions (balanced), vs the R1 stride-24 layout's 4 reachable groups / ~5-way.

#define M_SEQ 8192
#define L_POS 256
#define Q_SYM 21
#define QQ    441            // Q*Q
#define JC    16             // j-chunk staged to LDS per iteration
#define ROWF  32             // floats per (jc,b) row (128 B)
#define JC_STRIDE (Q_SYM * ROWF)   // 672 floats per jc

__device__ __forceinline__ float wave_block_reduce(float v, float* red, int tid) {
    #pragma unroll
    for (int off = 32; off > 0; off >>= 1) v += __shfl_down(v, off, 64);
    if ((tid & 63) == 0) red[tid >> 6] = v;
    __syncthreads();
    return red[0] + red[1] + red[2] + red[3];
}

__global__ void zero_out(float* __restrict__ out) { out[0] = 0.0f; }

// L2 reg: 1e-4 * sum_{j<i} J[i,j,:,:]^2 + 1e-6 * sum h^2.
// Reads only lower-triangle rows (231 MB instead of 462 MB).
// grid = (4, 256): blockIdx.y = i, blockIdx.x = q covers j in [64q, min(i,64q+64)).
__global__ __launch_bounds__(256) void reg_kernel(const float* __restrict__ J,
                                                  const float* __restrict__ h,
                                                  float* __restrict__ out) {
    __shared__ float red[4];
    const int tid = threadIdx.x;
    const int i = blockIdx.y;
    const int q = blockIdx.x;
    const int j0 = q * 64;
    const int nrows = min(i, j0 + 64) - j0;
    if (nrows <= 0 && q != 0) return;

    float lsum = 0.0f;
    if (nrows > 0) {
        const float* base = J + (size_t)(i * L_POS + j0) * QQ;   // 64-aligned bytes
        const int count = nrows * QQ;
        const int count4 = count >> 2;
        const float4* b4 = (const float4*)base;
        for (int t = tid; t < count4; t += 256) {
            float4 f = b4[t];
            lsum += f.x * f.x + f.y * f.y + f.z * f.z + f.w * f.w;
        }
        for (int t = (count4 << 2) + tid; t < count; t += 256) {
            float v = base[t];
            lsum += v * v;
        }
    }
    lsum *= 1e-4f;
    if (q == 0 && tid < Q_SYM) {
        float hv = h[i * Q_SYM + tid];
        lsum += 1e-6f * hv * hv;
    }
    float tot = wave_block_reduce(lsum, red, tid);
    if (tid == 0) atomicAdd(out, tot);
}

// One block per (m-chunk of 256, i). Each thread owns one m.
__global__ __launch_bounds__(256) void pair_nll_kernel(const int* __restrict__ X,
                                                       const float* __restrict__ W,
                                                       const float* __restrict__ h,
                                                       const float* __restrict__ J,
                                                       float* __restrict__ out) {
    __shared__ float JL[JC * JC_STRIDE];   // 16*672*4 = 43008 B
    __shared__ float red[4];

    const int tid = threadIdx.x;
    const int i  = blockIdx.y;
    const int m  = blockIdx.x * 256 + tid;
    const int* xrow = X + (size_t)m * L_POS;

    float acc[Q_SYM];
    #pragma unroll
    for (int a = 0; a < Q_SYM; ++a) acc[a] = 0.0f;

    for (int j0 = 0; j0 < i; j0 += JC) {
        // (i*256 + j0) is a multiple of 16 -> *441 floats -> 64-B aligned: float4 OK
        const float4* Jsrc4 = (const float4*)(J + ((size_t)i * L_POS + j0) * QQ);
        __syncthreads();   // protect previous chunk's LDS reads

        // stage + transpose + swizzle: 7056 floats = 1764 float4 loads
        for (int t = tid; t < (JC * QQ) / 4; t += 256) {
            float4 v = Jsrc4[t];
            int q4 = t << 2;
            int jc = q4 / QQ;            // const-divisor -> magic mul
            int r  = q4 - jc * QQ;
            int a  = r / Q_SYM;
            int b  = r - a * Q_SYM;
            float vals[4] = {v.x, v.y, v.z, v.w};
            #pragma unroll
            for (int c = 0; c < 4; ++c) {
                JL[((jc * Q_SYM + b) << 5) + ((((a >> 2) ^ (b & 7)) << 2) | (a & 3))] = vals[c];
                ++b;
                if (b == Q_SYM) { b = 0; ++a; if (a == Q_SYM) { a = 0; ++jc; } }
            }
        }
        __syncthreads();

        // this thread's 16 X values (row-contiguous, vectorized)
        int4 xa = *(const int4*)(xrow + j0);
        int4 xb = *(const int4*)(xrow + j0 + 4);
        int4 xc = *(const int4*)(xrow + j0 + 8);
        int4 xd = *(const int4*)(xrow + j0 + 12);
        int xv[JC] = {xa.x, xa.y, xa.z, xa.w, xb.x, xb.y, xb.z, xb.w,
                      xc.x, xc.y, xc.z, xc.w, xd.x, xd.y, xd.z, xd.w};

        #pragma unroll
        for (int jc = 0; jc < JC; ++jc) {
            if (j0 + jc < i) {   // block-uniform guard (scalar branch)
                int b  = xv[jc];
                int bb = b & 7;
                const float* row = JL + ((jc * Q_SYM + b) << 5);
                float4 f0 = *(const float4*)(row + ((0 ^ bb) << 2));
                float4 f1 = *(const float4*)(row + ((1 ^ bb) << 2));
                float4 f2 = *(const float4*)(row + ((2 ^ bb) << 2));
                float4 f3 = *(const float4*)(row + ((3 ^ bb) << 2));
                float4 f4 = *(const float4*)(row + ((4 ^ bb) << 2));
                float  g0 = row[((5 ^ bb) << 2)];
                acc[0]  += f0.x; acc[1]  += f0.y; acc[2]  += f0.z; acc[3]  += f0.w;
                acc[4]  += f1.x; acc[5]  += f1.y; acc[6]  += f1.z; acc[7]  += f1.w;
                acc[8]  += f2.x; acc[9]  += f2.y; acc[10] += f2.z; acc[11] += f2.w;
                acc[12] += f3.x; acc[13] += f3.y; acc[14] += f3.z; acc[15] += f3.w;
                acc[16] += f4.x; acc[17] += f4.y; acc[18] += f4.z; acc[19] += f4.w;
                acc[20] += g0;
            }
        }
    }

    // logits = h[i,:] + pair ; log-softmax ; pick gold = X[m,i]
    const float* hrow = h + i * Q_SYM;
    float logits[Q_SYM];
    float mx = -3.4e38f;
    #pragma unroll
    for (int a = 0; a < Q_SYM; ++a) {
        float l = hrow[a] + acc[a];
        logits[a] = l;
        mx = fmaxf(mx, l);
    }
    float s = 0.0f;
    #pragma unroll
    for (int a = 0; a < Q_SYM; ++a) s += __expf(logits[a] - mx);
    int g = xrow[i];
    float gold = 0.0f;
    #pragma unroll
    for (int a = 0; a < Q_SYM; ++a) gold = (a == g) ? logits[a] : gold;
    float logp = gold - mx - __logf(s);
    float v = -W[m] * logp;

    __syncthreads();   // JL/red reuse safety before reduction
    float tot = wave_block_reduce(v, red, tid);
    if (tid == 0) atomicAdd(out, tot);
}

extern "C" void kernel_launch(void* const* d_in, const int* in_sizes, int n_in,
                              void* d_out, int out_size, void* d_ws, size_t ws_size,
                              hipStream_t stream) {
    const int*   X = (const int*)d_in[0];
    const float* W = (const float*)d_in[1];
    const float* h = (const float*)d_in[2];
    const float* J = (const float*)d_in[3];
    float* out = (float*)d_out;

    hipLaunchKernelGGL(zero_out, dim3(1), dim3(1), 0, stream, out);
    hipLaunchKernelGGL(reg_kernel, dim3(4, L_POS), dim3(256), 0, stream, J, h, out);
    dim3 grid(M_SEQ / 256, L_POS);
    hipLaunchKernelGGL(pair_nll_kernel, grid, dim3(256), 0, stream, X, W, h, J, out);
}

// Round 3
// 547.115 us; speedup vs baseline: 1.5288x; 1.4810x over previous
//
#include <hip/hip_runtime.h>

// ArDCA loss: loss = -sum_{m,i} W[m] * log_softmax(h[i,:] + sum_{j<i} J[i,j,:,X[m,j]])[X[m,i]]
//             + 1e-6 * sum h^2 + 1e-4 * sum_{j<i} J^2
// M=8192, L=256, Q=21. Output: single fp32 scalar.
//
// R3: f16 LDS tiles. Row (jc,b) = 24 f16 (48 B): gather = 3 ds_read_b128,
// accumulate = 10 v_pk_add_f16 + 1 v_add_f16 (was 6 reads + 21 fp32 adds).
// Staging rows are thread-owned with offsets precomputed once (no per-chunk
// address math). Row stride 12 words -> row starts cover all 8 bank-groups;
// 21 rows over 8 groups = balanced 3-way worst case (pigeonhole floor).
// f16 error budget: J~N(0,1e-4), cast err 2^-11 rel; accum walk over <=255
// adds gives ~1e-3 per logit -> ~1e-4 on the loss vs threshold 15.6.

#define M_SEQ 8192
#define L_POS 256
#define Q_SYM 21
#define QQ    441
#define JC    16
#define NROWS (JC * Q_SYM)       // 336 rows per chunk

typedef _Float16 half2v __attribute__((ext_vector_type(2)));

__device__ __forceinline__ half2v as_h2(float x) {
    union { float f; half2v h; } u; u.f = x; return u.h;
}
__device__ __forceinline__ float pack2(float a, float b) {
    union { float f; half2v h; } u;
    u.h.x = (_Float16)a; u.h.y = (_Float16)b;
    return u.f;
}

__device__ __forceinline__ float wave_block_reduce(float v, float* red, int tid) {
    #pragma unroll
    for (int off = 32; off > 0; off >>= 1) v += __shfl_down(v, off, 64);
    if ((tid & 63) == 0) red[tid >> 6] = v;
    __syncthreads();
    return red[0] + red[1] + red[2] + red[3];
}

__global__ void zero_out(float* __restrict__ out) { out[0] = 0.0f; }

// L2 reg: 1e-4 * sum_{j<i} J^2 + 1e-6 * sum h^2 (lower-triangle rows only).
__global__ __launch_bounds__(256) void reg_kernel(const float* __restrict__ J,
                                                  const float* __restrict__ h,
                                                  float* __restrict__ out) {
    __shared__ float red[4];
    const int tid = threadIdx.x;
    const int i = blockIdx.y;
    const int q = blockIdx.x;
    const int j0 = q * 64;
    const int nrows = min(i, j0 + 64) - j0;
    if (nrows <= 0 && q != 0) return;

    float lsum = 0.0f;
    if (nrows > 0) {
        const float* base = J + (size_t)(i * L_POS + j0) * QQ;
        const int count = nrows * QQ;
        const int count4 = count >> 2;
        const float4* b4 = (const float4*)base;
        for (int t = tid; t < count4; t += 256) {
            float4 f = b4[t];
            lsum += f.x * f.x + f.y * f.y + f.z * f.z + f.w * f.w;
        }
        for (int t = (count4 << 2) + tid; t < count; t += 256) {
            float v = base[t];
            lsum += v * v;
        }
    }
    lsum *= 1e-4f;
    if (q == 0 && tid < Q_SYM) {
        float hv = h[i * Q_SYM + tid];
        lsum += 1e-6f * hv * hv;
    }
    float tot = wave_block_reduce(lsum, red, tid);
    if (tid == 0) atomicAdd(out, tot);
}

// One block per (m-chunk of 256, i). Each thread owns one m.
__global__ __launch_bounds__(256) void pair_nll_kernel(const int* __restrict__ X,
                                                       const float* __restrict__ W,
                                                       const float* __restrict__ h,
                                                       const float* __restrict__ J,
                                                       float* __restrict__ out) {
    __shared__ float4 JL4[NROWS * 3];    // 336 * 48 B = 16128 B
    __shared__ float red[4];

    const int tid = threadIdx.x;
    const int i  = blockIdx.y;
    const int m  = blockIdx.x * 256 + tid;
    const int* xrow = X + (size_t)m * L_POS;

    // thread-owned staging rows (fixed for whole kernel)
    const int row0 = tid;                       // 0..255
    const int jc0  = row0 / Q_SYM;
    const int b0   = row0 - jc0 * Q_SYM;
    const int row1 = tid + 256;                 // 256..335 valid when tid < 80
    const int jc1  = row1 / Q_SYM;
    const int b1   = row1 - jc1 * Q_SYM;
    const bool has_row1 = (row1 < NROWS);

    half2v acc[10];
    #pragma unroll
    for (int k = 0; k < 10; ++k) { acc[k].x = (_Float16)0.f; acc[k].y = (_Float16)0.f; }
    _Float16 acc20 = (_Float16)0.f;

    for (int j0 = 0; j0 < i; j0 += JC) {
        const float* Jsrc = J + ((size_t)i * L_POS + j0) * QQ;
        __syncthreads();   // protect previous chunk's LDS reads

        // ---- stage: each thread converts+packs its row(s); 3 ds_write_b128 each
        {
            const float* s = Jsrc + jc0 * QQ + b0;
            float v[Q_SYM];
            #pragma unroll
            for (int a = 0; a < Q_SYM; ++a) v[a] = s[a * Q_SYM];
            float4 p0, p1, p2;
            p0.x = pack2(v[0],  v[1]);  p0.y = pack2(v[2],  v[3]);
            p0.z = pack2(v[4],  v[5]);  p0.w = pack2(v[6],  v[7]);
            p1.x = pack2(v[8],  v[9]);  p1.y = pack2(v[10], v[11]);
            p1.z = pack2(v[12], v[13]); p1.w = pack2(v[14], v[15]);
            p2.x = pack2(v[16], v[17]); p2.y = pack2(v[18], v[19]);
            p2.z = pack2(v[20], 0.f);   p2.w = 0.f;
            float4* dst = JL4 + row0 * 3;
            dst[0] = p0; dst[1] = p1; dst[2] = p2;
        }
        if (has_row1) {
            const float* s = Jsrc + jc1 * QQ + b1;
            float v[Q_SYM];
            #pragma unroll
            for (int a = 0; a < Q_SYM; ++a) v[a] = s[a * Q_SYM];
            float4 p0, p1, p2;
            p0.x = pack2(v[0],  v[1]);  p0.y = pack2(v[2],  v[3]);
            p0.z = pack2(v[4],  v[5]);  p0.w = pack2(v[6],  v[7]);
            p1.x = pack2(v[8],  v[9]);  p1.y = pack2(v[10], v[11]);
            p1.z = pack2(v[12], v[13]); p1.w = pack2(v[14], v[15]);
            p2.x = pack2(v[16], v[17]); p2.y = pack2(v[18], v[19]);
            p2.z = pack2(v[20], 0.f);   p2.w = 0.f;
            float4* dst = JL4 + row1 * 3;
            dst[0] = p0; dst[1] = p1; dst[2] = p2;
        }
        __syncthreads();

        // ---- this thread's 16 X values (row-contiguous, vectorized)
        int4 xa = *(const int4*)(xrow + j0);
        int4 xb = *(const int4*)(xrow + j0 + 4);
        int4 xc = *(const int4*)(xrow + j0 + 8);
        int4 xd = *(const int4*)(xrow + j0 + 12);
        int xv[JC] = {xa.x, xa.y, xa.z, xa.w, xb.x, xb.y, xb.z, xb.w,
                      xc.x, xc.y, xc.z, xc.w, xd.x, xd.y, xd.z, xd.w};

        #pragma unroll
        for (int jc = 0; jc < JC; ++jc) {
            if (j0 + jc < i) {   // block-uniform guard (scalar branch)
                int b = xv[jc];
                const float4* r = JL4 + (jc * Q_SYM + b) * 3;
                float4 f0 = r[0];
                float4 f1 = r[1];
                float4 f2 = r[2];
                acc[0] += as_h2(f0.x); acc[1] += as_h2(f0.y);
                acc[2] += as_h2(f0.z); acc[3] += as_h2(f0.w);
                acc[4] += as_h2(f1.x); acc[5] += as_h2(f1.y);
                acc[6] += as_h2(f1.z); acc[7] += as_h2(f1.w);
                acc[8] += as_h2(f2.x); acc[9] += as_h2(f2.y);
                acc20  += as_h2(f2.z).x;
            }
        }
    }

    // ---- logits = h[i,:] + pair ; log-softmax ; pick gold = X[m,i]
    const float* hrow = h + i * Q_SYM;
    float logits[Q_SYM];
    #pragma unroll
    for (int k = 0; k < 10; ++k) {
        logits[2 * k]     = hrow[2 * k]     + (float)acc[k].x;
        logits[2 * k + 1] = hrow[2 * k + 1] + (float)acc[k].y;
    }
    logits[20] = hrow[20] + (float)acc20;

    float mx = -3.4e38f;
    #pragma unroll
    for (int a = 0; a < Q_SYM; ++a) mx = fmaxf(mx, logits[a]);
    float s = 0.0f;
    #pragma unroll
    for (int a = 0; a < Q_SYM; ++a) s += __expf(logits[a] - mx);
    int g = xrow[i];
    float gold = 0.0f;
    #pragma unroll
    for (int a = 0; a < Q_SYM; ++a) gold = (a == g) ? logits[a] : gold;
    float logp = gold - mx - __logf(s);
    float v = -W[m] * logp;

    __syncthreads();   // LDS reuse safety before reduction
    float tot = wave_block_reduce(v, red, tid);
    if (tid == 0) atomicAdd(out, tot);
}

extern "C" void kernel_launch(void* const* d_in, const int* in_sizes, int n_in,
                              void* d_out, int out_size, void* d_ws, size_t ws_size,
                              hipStream_t stream) {
    const int*   X = (const int*)d_in[0];
    const float* W = (const float*)d_in[1];
    const float* h = (const float*)d_in[2];
    const float* J = (const float*)d_in[3];
    float* out = (float*)d_out;

    hipLaunchKernelGGL(zero_out, dim3(1), dim3(1), 0, stream, out);
    hipLaunchKernelGGL(reg_kernel, dim3(4, L_POS), dim3(256), 0, stream, J, h, out);
    dim3 grid(M_SEQ / 256, L_POS);
    hipLaunchKernelGGL(pair_nll_kernel, grid, dim3(256), 0, stream, X, W, h, J, out);
}

// Round 4
// 525.636 us; speedup vs baseline: 1.5913x; 1.0409x over previous
//
#include <hip/hip_runtime.h>

// ArDCA loss: loss = -sum_{m,i} W[m] * log_softmax(h[i,:] + sum_{j<i} J[i,j,:,X[m,j]])[X[m,i]]
//             + 1e-6 * sum h^2 + 1e-4 * sum_{j<i} J^2
// M=8192, L=256, Q=21. Output: single fp32 scalar.
//
// R4: reg_kernel folded into pair_nll staging. The staging loop of the
// blockIdx.x==0 blocks reads exactly the lower-triangle J values in fp32
// (before f16 packing), so sum J^2 is accumulated there for free; the h^2
// term rides the epilogue. Saves the separate 231 MB reg pass (~130 us).
//
// Pair structure (R3, measured ~85% LDS-data-path-bound, near its floor):
// f16 LDS rows of 24 (48 B), gather = 3 ds_read_b128, accumulate =
// 10 v_pk_add_f16 + 1. Conflicts at the pigeonhole floor (21 rows over
// 8 bank-groups, avg 2.6 addr/bank).

#define M_SEQ 8192
#define L_POS 256
#define Q_SYM 21
#define QQ    441
#define JC    16
#define NROWS (JC * Q_SYM)       // 336 rows per chunk

typedef _Float16 half2v __attribute__((ext_vector_type(2)));

__device__ __forceinline__ half2v as_h2(float x) {
    union { float f; half2v h; } u; u.f = x; return u.h;
}
__device__ __forceinline__ float pack2(float a, float b) {
    union { float f; half2v h; } u;
    u.h.x = (_Float16)a; u.h.y = (_Float16)b;
    return u.f;
}

__device__ __forceinline__ float wave_block_reduce(float v, float* red, int tid) {
    #pragma unroll
    for (int off = 32; off > 0; off >>= 1) v += __shfl_down(v, off, 64);
    if ((tid & 63) == 0) red[tid >> 6] = v;
    __syncthreads();
    return red[0] + red[1] + red[2] + red[3];
}

__global__ void zero_out(float* __restrict__ out) { out[0] = 0.0f; }

// One block per (m-chunk of 256, i). Each thread owns one m.
__global__ __launch_bounds__(256) void pair_nll_kernel(const int* __restrict__ X,
                                                       const float* __restrict__ W,
                                                       const float* __restrict__ h,
                                                       const float* __restrict__ J,
                                                       float* __restrict__ out) {
    __shared__ float4 JL4[NROWS * 3];    // 336 * 48 B = 16128 B
    __shared__ float red[4];

    const int tid = threadIdx.x;
    const int i  = blockIdx.y;
    const int m  = blockIdx.x * 256 + tid;
    const bool do_reg = (blockIdx.x == 0);
    const int* xrow = X + (size_t)m * L_POS;

    // thread-owned staging rows (fixed for whole kernel)
    const int row0 = tid;                       // 0..255
    const int jc0  = row0 / Q_SYM;
    const int b0   = row0 - jc0 * Q_SYM;
    const int row1 = tid + 256;                 // 256..335 valid when tid < 80
    const int jc1  = row1 / Q_SYM;
    const int b1   = row1 - jc1 * Q_SYM;
    const bool has_row1 = (row1 < NROWS);

    half2v acc[10];
    #pragma unroll
    for (int k = 0; k < 10; ++k) { acc[k].x = (_Float16)0.f; acc[k].y = (_Float16)0.f; }
    _Float16 acc20 = (_Float16)0.f;
    float regsum = 0.0f;   // sum of J^2 over this thread's staged (i, j<i, :, b) values

    for (int j0 = 0; j0 < i; j0 += JC) {
        const float* Jsrc = J + ((size_t)i * L_POS + j0) * QQ;
        __syncthreads();   // protect previous chunk's LDS reads

        // ---- stage: each thread converts+packs its row(s); 3 ds_write_b128 each
        {
            const float* s = Jsrc + jc0 * QQ + b0;
            float v[Q_SYM];
            #pragma unroll
            for (int a = 0; a < Q_SYM; ++a) v[a] = s[a * Q_SYM];
            if (do_reg && (j0 + jc0 < i)) {
                float rs = 0.0f;
                #pragma unroll
                for (int a = 0; a < Q_SYM; ++a) rs += v[a] * v[a];
                regsum += rs;
            }
            float4 p0, p1, p2;
            p0.x = pack2(v[0],  v[1]);  p0.y = pack2(v[2],  v[3]);
            p0.z = pack2(v[4],  v[5]);  p0.w = pack2(v[6],  v[7]);
            p1.x = pack2(v[8],  v[9]);  p1.y = pack2(v[10], v[11]);
            p1.z = pack2(v[12], v[13]); p1.w = pack2(v[14], v[15]);
            p2.x = pack2(v[16], v[17]); p2.y = pack2(v[18], v[19]);
            p2.z = pack2(v[20], 0.f);   p2.w = 0.f;
            float4* dst = JL4 + row0 * 3;
            dst[0] = p0; dst[1] = p1; dst[2] = p2;
        }
        if (has_row1) {
            const float* s = Jsrc + jc1 * QQ + b1;
            float v[Q_SYM];
            #pragma unroll
            for (int a = 0; a < Q_SYM; ++a) v[a] = s[a * Q_SYM];
            if (do_reg && (j0 + jc1 < i)) {
                float rs = 0.0f;
                #pragma unroll
                for (int a = 0; a < Q_SYM; ++a) rs += v[a] * v[a];
                regsum += rs;
            }
            float4 p0, p1, p2;
            p0.x = pack2(v[0],  v[1]);  p0.y = pack2(v[2],  v[3]);
            p0.z = pack2(v[4],  v[5]);  p0.w = pack2(v[6],  v[7]);
            p1.x = pack2(v[8],  v[9]);  p1.y = pack2(v[10], v[11]);
            p1.z = pack2(v[12], v[13]); p1.w = pack2(v[14], v[15]);
            p2.x = pack2(v[16], v[17]); p2.y = pack2(v[18], v[19]);
            p2.z = pack2(v[20], 0.f);   p2.w = 0.f;
            float4* dst = JL4 + row1 * 3;
            dst[0] = p0; dst[1] = p1; dst[2] = p2;
        }
        __syncthreads();

        // ---- this thread's 16 X values (row-contiguous, vectorized)
        int4 xa = *(const int4*)(xrow + j0);
        int4 xb = *(const int4*)(xrow + j0 + 4);
        int4 xc = *(const int4*)(xrow + j0 + 8);
        int4 xd = *(const int4*)(xrow + j0 + 12);
        int xv[JC] = {xa.x, xa.y, xa.z, xa.w, xb.x, xb.y, xb.z, xb.w,
                      xc.x, xc.y, xc.z, xc.w, xd.x, xd.y, xd.z, xd.w};

        #pragma unroll
        for (int jc = 0; jc < JC; ++jc) {
            if (j0 + jc < i) {   // block-uniform guard (scalar branch)
                int b = xv[jc];
                const float4* r = JL4 + (jc * Q_SYM + b) * 3;
                float4 f0 = r[0];
                float4 f1 = r[1];
                float4 f2 = r[2];
                acc[0] += as_h2(f0.x); acc[1] += as_h2(f0.y);
                acc[2] += as_h2(f0.z); acc[3] += as_h2(f0.w);
                acc[4] += as_h2(f1.x); acc[5] += as_h2(f1.y);
                acc[6] += as_h2(f1.z); acc[7] += as_h2(f1.w);
                acc[8] += as_h2(f2.x); acc[9] += as_h2(f2.y);
                acc20  += as_h2(f2.z).x;
            }
        }
    }

    // ---- logits = h[i,:] + pair ; log-softmax ; pick gold = X[m,i]
    const float* hrow = h + i * Q_SYM;
    float logits[Q_SYM];
    #pragma unroll
    for (int k = 0; k < 10; ++k) {
        logits[2 * k]     = hrow[2 * k]     + (float)acc[k].x;
        logits[2 * k + 1] = hrow[2 * k + 1] + (float)acc[k].y;
    }
    logits[20] = hrow[20] + (float)acc20;

    float mx = -3.4e38f;
    #pragma unroll
    for (int a = 0; a < Q_SYM; ++a) mx = fmaxf(mx, logits[a]);
    float s = 0.0f;
    #pragma unroll
    for (int a = 0; a < Q_SYM; ++a) s += __expf(logits[a] - mx);
    int g = xrow[i];
    float gold = 0.0f;
    #pragma unroll
    for (int a = 0; a < Q_SYM; ++a) gold = (a == g) ? logits[a] : gold;
    float logp = gold - mx - __logf(s);
    float v = -W[m] * logp;

    // ---- fold regularization terms (blockIdx.x==0 blocks only; each (i,j,a,b)
    //      of the lower triangle counted exactly once across those blocks)
    if (do_reg) {
        v += 1e-4f * regsum;
        if (tid < Q_SYM) {
            float hv = hrow[tid];
            v += 1e-6f * hv * hv;
        }
    }

    __syncthreads();   // LDS reuse safety before reduction
    float tot = wave_block_reduce(v, red, tid);
    if (tid == 0) atomicAdd(out, tot);
}

extern "C" void kernel_launch(void* const* d_in, const int* in_sizes, int n_in,
                              void* d_out, int out_size, void* d_ws, size_t ws_size,
                              hipStream_t stream) {
    const int*   X = (const int*)d_in[0];
    const float* W = (const float*)d_in[1];
    const float* h = (const float*)d_in[2];
    const float* J = (const float*)d_in[3];
    float* out = (float*)d_out;

    hipLaunchKernelGGL(zero_out, dim3(1), dim3(1), 0, stream, out);
    dim3 grid(M_SEQ / 256, L_POS);
    hipLaunchKernelGGL(pair_nll_kernel, grid, dim3(256), 0, stream, X, W, h, J, out);
}